// Round 7
// baseline (1036.813 us; speedup 1.0000x reference)
//
#include <hip/hip_runtime.h>
#include <hip/hip_bf16.h>

#define B_  2
#define T_  2048
#define H_  2048
#define NH_ 16
#define HD_ 128
#define QKVN 6144

typedef __attribute__((ext_vector_type(8))) short  short8;   // 8 bf16 in 4 VGPRs
typedef __attribute__((ext_vector_type(4))) float  floatx4;  // MFMA C/D

__device__ __forceinline__ unsigned short f2bf(float x) {
    union { float f; unsigned int u; } c; c.f = x;
    unsigned int r = c.u + 0x7FFF + ((c.u >> 16) & 1);   // RNE
    return (unsigned short)(r >> 16);
}
__device__ __forceinline__ float bf2f(unsigned short u) {
    union { float f; unsigned int i; } c;
    c.i = ((unsigned int)u) << 16;
    return c.f;
}

// async global->LDS, 16B per lane; LDS dest is wave-uniform base + lane*16
__device__ __forceinline__ void gload_lds16(const void* g, void* l) {
    __builtin_amdgcn_global_load_lds(
        (__attribute__((address_space(1))) void*)g,
        (__attribute__((address_space(3))) void*)l, 16, 0, 0);
}

// ---------------- fp32 -> bf16 convert (vector4) ---------------------------------
__global__ __launch_bounds__(256) void f32_to_bf16(
    const float* __restrict__ src, unsigned short* __restrict__ dst, int n)
{
    const int i = (blockIdx.x * 256 + threadIdx.x) * 4;
    if (i < n) {
        float4 v = *(const float4*)(src + i);
        ushort4 o;
        o.x = f2bf(v.x); o.y = f2bf(v.y); o.z = f2bf(v.z); o.w = f2bf(v.w);
        *(ushort4*)(dst + i) = o;
    }
}

// ---------------- gemm8 fragment helpers ------------------------------------------
template<int MB>
__device__ __forceinline__ void ld_a4(short8 (&d)[4][2], const unsigned short* src,
                                      int wm, int n16, int quad)
{
    #pragma unroll
    for (int mi = 0; mi < 4; ++mi)
        #pragma unroll
        for (int ks = 0; ks < 2; ++ks)
            d[mi][ks] = *(const short8*)(src + (wm*128 + (MB+mi)*16 + n16) * 64
                                             + (((ks*4 + quad) ^ (n16 & 7)) * 8));
}
template<int NB>
__device__ __forceinline__ void ld_b2(short8 (&d)[2][2], const unsigned short* src,
                                      int wn, int n16, int quad)
{
    #pragma unroll
    for (int ni = 0; ni < 2; ++ni)
        #pragma unroll
        for (int ks = 0; ks < 2; ++ks)
            d[ni][ks] = *(const short8*)(src + (wn*64 + (NB+ni)*16 + n16) * 64
                                             + (((ks*4 + quad) ^ (n16 & 7)) * 8));
}
// one C-quadrant x K=64: 16 MFMA
template<int MB, int NB>
__device__ __forceinline__ void mfma_q(floatx4 (&acc)[8][4],
                                       const short8 (&a)[4][2],
                                       const short8 (&b)[2][2])
{
    #pragma unroll
    for (int ks = 0; ks < 2; ++ks)
        #pragma unroll
        for (int mi = 0; mi < 4; ++mi)
            #pragma unroll
            for (int ni = 0; ni < 2; ++ni)
                acc[MB+mi][NB+ni] = __builtin_amdgcn_mfma_f32_16x16x32_bf16(
                    a[mi][ks], b[ni][ks], acc[MB+mi][NB+ni], 0, 0, 0);
}

#define BAR()   asm volatile("s_barrier" ::: "memory")
#define SBAR()  __builtin_amdgcn_sched_barrier(0)
#define LGKM(n) do { asm volatile("s_waitcnt lgkmcnt(" #n ")" ::: "memory"); SBAR(); } while (0)

// ---------------- one K-tile: balanced read-ahead quadrant phases ----------------
// Quadrant order Q00 -> Q10 -> Q01 -> Q11. Reads spread so per-phase LDS time
// <= MFMA time and every pre-MFMA wait is a COUNTED lgkmcnt:
//   prev-P4 (after publish-BAR): afL+bfL for NEXT tile (12 rds, hidden under Q11)
//   P1: afH (8 rds) + stage A(t+1) | BAR | lgkm(8)  | MFMA Q00 | BAR
//   P2: bfH (4 rds) + stage B(t+1) | BAR | lgkm(4)  | MFMA Q10 | BAR
//   P3:                                    lgkm(0)  | MFMA Q01 | BAR
//   P4: vmcnt(0) [2-phase cover] | BAR(publish) | rd afL'/bfL' | MFMA Q11 (no wait) | BAR
__device__ __forceinline__ void g5_tile(
    const unsigned short* Ac, const unsigned short* Bc,
    unsigned short* An, unsigned short* Bn,
    const unsigned short* A0p, const unsigned short* A1p,
    const unsigned short* B0p, const unsigned short* B1p,
    size_t hstep, size_t knext, bool pre, int tid,
    int wm, int wn, int n16, int quad,
    short8 (&afLc)[4][2], short8 (&bfLc)[2][2],   // this tile's LO frags (pre-loaded)
    short8 (&afLn)[4][2], short8 (&bfLn)[2][2],   // next tile's LO frags (loaded at P4)
    short8 (&afH)[4][2],  short8 (&bfH)[2][2],
    floatx4 (&acc)[8][4])
{
    // ---- P1: Q(0,0) ----
    ld_a4<4>(afH, Ac, wm, n16, quad);            // 8 reads, used at P2
    if (pre) {
        gload_lds16(A0p + knext,         An + (size_t)tid * 8);
        gload_lds16(A1p + knext,         An + (size_t)(tid + 512) * 8);
        gload_lds16(A0p + knext + hstep, An + 8192 + (size_t)tid * 8);
        gload_lds16(A1p + knext + hstep, An + 8192 + (size_t)(tid + 512) * 8);
    }
    BAR();
    LGKM(8);                                     // afLc+bfLc (12, from prev P4) ready
    __builtin_amdgcn_s_setprio(1);
    mfma_q<0, 0>(acc, afLc, bfLc);
    __builtin_amdgcn_s_setprio(0);
    BAR();

    // ---- P2: Q(1,0) ----
    ld_b2<2>(bfH, Bc, wn, n16, quad);            // 4 reads, used at P3
    if (pre) {
        gload_lds16(B0p + knext,         Bn + (size_t)tid * 8);
        gload_lds16(B1p + knext,         Bn + (size_t)(tid + 512) * 8);
        gload_lds16(B0p + knext + hstep, Bn + 8192 + (size_t)tid * 8);
        gload_lds16(B1p + knext + hstep, Bn + 8192 + (size_t)(tid + 512) * 8);
    }
    BAR();
    LGKM(4);                                     // afH ready
    __builtin_amdgcn_s_setprio(1);
    mfma_q<4, 0>(acc, afH, bfLc);
    __builtin_amdgcn_s_setprio(0);
    BAR();

    // ---- P3: Q(0,1) ----
    LGKM(0);                                     // bfH ready
    __builtin_amdgcn_s_setprio(1);
    mfma_q<0, 2>(acc, afLc, bfH);
    __builtin_amdgcn_s_setprio(0);
    BAR();

    // ---- P4: Q(1,1) ----
    asm volatile("s_waitcnt vmcnt(0)" ::: "memory");  // staging landed (~2-phase cover)
    BAR();                                            // publish buf[t+1] to all waves
    if (pre) {                                        // 12 reads for next tile's P1,
        ld_a4<0>(afLn, An, wm, n16, quad);            // hidden under Q11's MFMA
        ld_b2<0>(bfLn, Bn, wn, n16, quad);
    }
    SBAR();
    __builtin_amdgcn_s_setprio(1);
    mfma_q<4, 2>(acc, afH, bfH);                      // operands already waited (P2/P3)
    __builtin_amdgcn_s_setprio(0);
    BAR();
}

// ---------------- 256x256 balanced-phase bf16 GEMM: Y = A[M,K] @ W[N,K]^T --------
// 8 waves (2Mx4N), BK=64, dbuf 128KB LDS, granule-XOR swizzle both-sides,
// counted lgkm/vmcnt, read-ahead across tile boundary via alternating LO-sets.
template<bool BF16_OUT>
__global__ __launch_bounds__(512, 1) void gemm8(
    const unsigned short* __restrict__ A,   // [M,K] bf16
    const unsigned short* __restrict__ W,   // [N,K] bf16
    float* __restrict__ Yf, unsigned short* __restrict__ Yb,
    int M, int N, int K)
{
    __shared__ __attribute__((aligned(16))) unsigned short As[2][256 * 64]; // 64 KB
    __shared__ __attribute__((aligned(16))) unsigned short Bs[2][256 * 64]; // 64 KB

    const int tid  = threadIdx.x;
    const int lane = tid & 63;
    const int n16  = lane & 15;
    const int quad = lane >> 4;
    const int w    = tid >> 6;      // 0..7
    const int wm   = w >> 2;        // 0..1  (128-row panel)
    const int wn   = w & 3;         // 0..3  (64-col panel)

    const int m0 = blockIdx.y * 256;
    const int n0 = blockIdx.x * 256;

    // staging: slot s = i*512+tid -> LDS row r = s>>3 (within half), granule s&7.
    // source granule = (s&7) ^ (r&7)  (involution; read side XORs the same way)
    const int r0  = tid >> 3;
    const int g0  = ((tid & 7) ^ (r0 & 7)) * 8;
    const unsigned short* A0p = A + (size_t)(m0 + r0) * K + g0;
    const unsigned short* A1p = A + (size_t)(m0 + 64 + r0) * K + g0;  // (r+64)&7 == r&7
    const unsigned short* B0p = W + (size_t)(n0 + r0) * K + g0;
    const unsigned short* B1p = W + (size_t)(n0 + 64 + r0) * K + g0;
    const size_t hstep = (size_t)128 * K;   // +128 rows (second half-tile)

    floatx4 acc[8][4];
    #pragma unroll
    for (int i = 0; i < 8; i++)
        #pragma unroll
        for (int j = 0; j < 4; j++) acc[i][j] = (floatx4){0.f, 0.f, 0.f, 0.f};

    const int nt = K >> 6;          // 32 for K=2048 (even; loop unrolled by 2)

    // prologue: stage tile 0 into buf 0, drain, publish, preload tile-0 LO frags
    gload_lds16(A0p,         &As[0][(size_t)tid * 8]);
    gload_lds16(A1p,         &As[0][(size_t)(tid + 512) * 8]);
    gload_lds16(A0p + hstep, &As[0][8192 + (size_t)tid * 8]);
    gload_lds16(A1p + hstep, &As[0][8192 + (size_t)(tid + 512) * 8]);
    gload_lds16(B0p,         &Bs[0][(size_t)tid * 8]);
    gload_lds16(B1p,         &Bs[0][(size_t)(tid + 512) * 8]);
    gload_lds16(B0p + hstep, &Bs[0][8192 + (size_t)tid * 8]);
    gload_lds16(B1p + hstep, &Bs[0][8192 + (size_t)(tid + 512) * 8]);
    asm volatile("s_waitcnt vmcnt(0)" ::: "memory");
    BAR();

    short8 afL0[4][2], bfL0[2][2], afL1[4][2], bfL1[2][2], afH[4][2], bfH[2][2];
    ld_a4<0>(afL0, &As[0][0], wm, n16, quad);   // 12 reads; waited at tile-0 P1 lgkm(8)
    ld_b2<0>(bfL0, &Bs[0][0], wn, n16, quad);

    for (int t = 0; t < nt; t += 2) {
        g5_tile(&As[0][0], &Bs[0][0], &As[1][0], &Bs[1][0],
                A0p, A1p, B0p, B1p, hstep,
                (size_t)(t + 1) << 6, (t + 1) < nt,
                tid, wm, wn, n16, quad,
                afL0, bfL0, afL1, bfL1, afH, bfH, acc);
        g5_tile(&As[1][0], &Bs[1][0], &As[0][0], &Bs[0][0],
                A0p, A1p, B0p, B1p, hstep,
                (size_t)(t + 2) << 6, (t + 2) < nt,
                tid, wm, wn, n16, quad,
                afL1, bfL1, afL0, bfL0, afH, bfH, acc);
    }

    // C/D: col = lane&15, row = quad*4 + reg  (verified m89/m91)
    #pragma unroll
    for (int mi = 0; mi < 8; ++mi) {
        const size_t rb = (size_t)(m0 + wm*128 + mi*16 + quad*4);
        #pragma unroll
        for (int r = 0; r < 4; ++r) {
            const size_t row = rb + r;
            #pragma unroll
            for (int ni = 0; ni < 4; ++ni) {
                const size_t col = n0 + wn*64 + ni*16 + n16;
                if (BF16_OUT) Yb[row * N + col] = f2bf(acc[mi][ni][r]);
                else          Yf[row * N + col] = acc[mi][ni][r];
            }
        }
    }
}

// ---------------- RoPE: bf16 qkv[:, 0:4096] -> bf16 [BH][T][HD] (q scaled) -------
__global__ __launch_bounds__(256) void rope_convert_qk(
    const unsigned short* __restrict__ qkvp,   // [B*T, 6144]
    const float* __restrict__ cosp, const float* __restrict__ sinp,
    unsigned short* __restrict__ qh, unsigned short* __restrict__ kh)
{
    const int idx  = blockIdx.x * 256 + threadIdx.x;
    const int d    = idx & 63;
    const int rest = idx >> 6;
    const int h    = rest & 15;
    const int bt   = rest >> 4;
    const int t    = bt & (T_ - 1);
    const int b    = bt >> 11;                       // T_ = 2048
    const size_t ibase = (size_t)bt * QKVN + h * HD_;
    const size_t obase = (((size_t)b * NH_ + h) * T_ + t) * HD_;

    const float c0 = cosp[t*HD_ + d],      s0 = sinp[t*HD_ + d];
    const float c1 = cosp[t*HD_ + d + 64], s1 = sinp[t*HD_ + d + 64];
    const float sc = 0.08838834764831845f;           // 1/sqrt(128)

    float q0 = bf2f(qkvp[ibase + d]), q1 = bf2f(qkvp[ibase + d + 64]);
    qh[obase + d]      = f2bf((q0*c0 - q1*s0) * sc);
    qh[obase + d + 64] = f2bf((q1*c1 + q0*s1) * sc);

    float k0 = bf2f(qkvp[ibase + 2048 + d]), k1 = bf2f(qkvp[ibase + 2048 + d + 64]);
    kh[obase + d]      = f2bf(k0*c0 - k1*s0);
    kh[obase + d + 64] = f2bf(k1*c1 + k0*s1);
}

// ---------------- V transpose: qkv[:, 4096:6144] -> bf16 [BH][HD][T] -------------
__global__ __launch_bounds__(256) void transpose_v(
    const unsigned short* __restrict__ qkvp, unsigned short* __restrict__ vh)
{
    __shared__ float tile[64][65];
    const int t0 = blockIdx.x * 64;
    const int d0 = blockIdx.y * 64;
    const int bh = blockIdx.z;
    const int b  = bh >> 4, h = bh & 15;

    for (int i = threadIdx.x; i < 4096; i += 256) {
        int r = i >> 6, c = i & 63;
        tile[r][c] = bf2f(qkvp[((size_t)b*T_ + t0 + r) * QKVN + 4096 + h*HD_ + d0 + c]);
    }
    __syncthreads();
    for (int i = threadIdx.x; i < 4096; i += 256) {
        int dr = i >> 6, tc = i & 63;
        vh[((size_t)bh * HD_ + d0 + dr) * T_ + t0 + tc] = f2bf(tile[tc][dr]);  // exact round-trip
    }
}

// ---------------- MFMA flash attention (round-0 verified) ------------------------
__global__ __launch_bounds__(256, 4) void attn_mfma(
    const unsigned short* __restrict__ qh,   // [BH][T][HD] (pre-scaled)
    const unsigned short* __restrict__ kh,   // [BH][T][HD]
    const unsigned short* __restrict__ vh,   // [BH][HD][T]
    unsigned short* __restrict__ o)          // [B][T][H] bf16
{
    __shared__ __attribute__((aligned(16))) unsigned short Ks[64 * 128];   // 16 KB
    __shared__ __attribute__((aligned(16))) unsigned short Vs[128 * 64];   // 16 KB
    __shared__ __attribute__((aligned(16))) unsigned short Ps[4][16 * 64]; //  8 KB

    const int tid  = threadIdx.x;
    const int lane = tid & 63;
    const int w    = tid >> 6;
    const int n16  = lane & 15;
    const int quad = lane >> 4;

    // work-balanced bijective remap: per-CU {a,a+8,23-a,31-a} = 66 tiles, shared bh
    const int id   = blockIdx.y * gridDim.x + blockIdx.x;
    const int bh   = id & 31;
    const int a    = (id >> 5) & 7;
    const int u    = id >> 8;
    const int qblk = (u < 2) ? (a + (u << 3)) : ((23 + ((u & 1) << 3)) - a);

    const int q0w  = qblk * 64 + w * 16;

    short8 qf[4];
    {
        const size_t qbase = ((size_t)bh * T_ + q0w + n16) * HD_ + quad * 8;
        #pragma unroll
        for (int c = 0; c < 4; c++)
            qf[c] = *(const short8*)(qh + qbase + c * 32);
    }

    const int rk   = tid >> 4;
    const int gk16 = ((tid & 15) ^ (rk & 7)) * 8;
    const unsigned short* ksrc = kh + (size_t)bh * T_ * HD_ + (size_t)rk * HD_ + gk16;
    const int dv   = tid >> 3;
    const int gv16 = ((tid & 7) ^ (dv & 7)) * 8;
    const unsigned short* vsrc = vh + (size_t)bh * HD_ * T_ + (size_t)dv * T_ + gv16;

    floatx4 of[8];
    #pragma unroll
    for (int i = 0; i < 8; i++) of[i] = (floatx4){0.f, 0.f, 0.f, 0.f};
    float mrow[4], lrow[4];
    #pragma unroll
    for (int r = 0; r < 4; r++) { mrow[r] = -INFINITY; lrow[r] = 0.f; }

    const int nkv = qblk + 1;
    for (int kv = 0; kv < nkv; kv++) {
        const int kv0 = kv * 64;
        __syncthreads();
        #pragma unroll
        for (int it = 0; it < 4; it++)
            gload_lds16(ksrc + (size_t)(kv0 + it * 16) * HD_,
                        Ks + (size_t)(it * 256 + tid) * 8);
        #pragma unroll
        for (int it = 0; it < 4; it++)
            gload_lds16(vsrc + kv0 + (size_t)(it * 32) * T_,
                        Vs + (size_t)(it * 256 + tid) * 8);
        __syncthreads();   // compiler drains vmcnt(0) before s_barrier

        floatx4 s[4];
        #pragma unroll
        for (int kg = 0; kg < 4; kg++) {
            floatx4 acc = {0.f, 0.f, 0.f, 0.f};
            #pragma unroll
            for (int c = 0; c < 4; c++) {
                short8 kf = *(const short8*)(Ks + (kg*16 + n16) * 128
                                                + (((c*4 + quad) ^ (n16 & 7)) * 8));
                acc = __builtin_amdgcn_mfma_f32_16x16x32_bf16(qf[c], kf, acc, 0, 0, 0);
            }
            s[kg] = acc;
        }

        const bool needmask = (kv0 + 63 > q0w);

        float alpha[4];
        #pragma unroll
        for (int r = 0; r < 4; r++) {
            const int qrow = q0w + quad * 4 + r;
            float v0 = s[0][r], v1 = s[1][r], v2 = s[2][r], v3 = s[3][r];
            if (needmask) {
                if (kv0 +  0 + n16 > qrow) v0 = -INFINITY;
                if (kv0 + 16 + n16 > qrow) v1 = -INFINITY;
                if (kv0 + 32 + n16 > qrow) v2 = -INFINITY;
                if (kv0 + 48 + n16 > qrow) v3 = -INFINITY;
            }

            float tm = fmaxf(fmaxf(v0, v1), fmaxf(v2, v3));
            tm = fmaxf(tm, __shfl_xor(tm, 1));
            tm = fmaxf(tm, __shfl_xor(tm, 2));
            tm = fmaxf(tm, __shfl_xor(tm, 4));
            tm = fmaxf(tm, __shfl_xor(tm, 8));

            const float mnew = fmaxf(mrow[r], tm);
            const float aa   = __expf(mrow[r] - mnew);
            const float p0 = __expf(v0 - mnew), p1 = __expf(v1 - mnew);
            const float p2 = __expf(v2 - mnew), p3 = __expf(v3 - mnew);

            float ts = p0 + p1 + p2 + p3;
            ts += __shfl_xor(ts, 1);
            ts += __shfl_xor(ts, 2);
            ts += __shfl_xor(ts, 4);
            ts += __shfl_xor(ts, 8);

            lrow[r] = lrow[r] * aa + ts;
            mrow[r] = mnew;
            alpha[r] = aa;

            const int pr = quad * 4 + r;
            const int sx = pr & 7;
            unsigned short* pp = &Ps[w][pr * 64];
            const int g0p = n16 >> 3, e = n16 & 7;
            pp[((g0p    ) ^ sx) * 8 + e] = f2bf(p0);
            pp[((g0p + 2) ^ sx) * 8 + e] = f2bf(p1);
            pp[((g0p + 4) ^ sx) * 8 + e] = f2bf(p2);
            pp[((g0p + 6) ^ sx) * 8 + e] = f2bf(p3);
        }
        #pragma unroll
        for (int nt = 0; nt < 8; nt++)
            #pragma unroll
            for (int r = 0; r < 4; r++) of[nt][r] *= alpha[r];

        short8 pf0 = *(const short8*)(&Ps[w][n16 * 64 + ((quad       ^ (n16 & 7)) * 8)]);
        short8 pf1 = *(const short8*)(&Ps[w][n16 * 64 + (((quad + 4) ^ (n16 & 7)) * 8)]);
        #pragma unroll
        for (int nt = 0; nt < 8; nt++) {
            const int vr = (nt * 16 + n16) * 64;
            short8 vf0 = *(const short8*)(Vs + vr + ((quad       ^ (n16 & 7)) * 8));
            short8 vf1 = *(const short8*)(Vs + vr + (((quad + 4) ^ (n16 & 7)) * 8));
            of[nt] = __builtin_amdgcn_mfma_f32_16x16x32_bf16(pf0, vf0, of[nt], 0, 0, 0);
            of[nt] = __builtin_amdgcn_mfma_f32_16x16x32_bf16(pf1, vf1, of[nt], 0, 0, 0);
        }
    }

    const int b = bh >> 4, h = bh & 15;
    #pragma unroll
    for (int r = 0; r < 4; r++) {
        const float inv = 1.f / lrow[r];
        const size_t orow = ((size_t)b * T_ + q0w + quad*4 + r) * H_ + h * HD_;
        #pragma unroll
        for (int nt = 0; nt < 8; nt++)
            o[orow + nt*16 + n16] = f2bf(of[nt][r] * inv);
    }
}

extern "C" void kernel_launch(void* const* d_in, const int* in_sizes, int n_in,
                              void* d_out, int out_size, void* d_ws, size_t ws_size,
                              hipStream_t stream)
{
    const float* x    = (const float*)d_in[0];
    const float* cosp = (const float*)d_in[1];
    const float* sinp = (const float*)d_in[2];
    const float* Wq   = (const float*)d_in[3];
    const float* Wk   = (const float*)d_in[4];
    const float* Wv   = (const float*)d_in[5];
    const float* Wo   = (const float*)d_in[6];

    const size_t NEL  = (size_t)B_ * T_ * H_;   // 8388608
    const int    XN   = (int)NEL;
    const int    WN   = H_ * H_;                // 4194304 per weight
    char* ws = (char*)d_ws;
    const size_t MB16 = 16777216;               // 16 MiB unit

    // overlay plan (total 7*MB16 = 117.4 MB):
    unsigned short* xh    = (unsigned short*)(ws);                // [0,1)   16.78MB
    unsigned short* Wqkvh = (unsigned short*)(ws + MB16);         // [1,2.5) 25.17MB
    unsigned short* Woh   = (unsigned short*)(ws + MB16*5/2);     // [2.5,3)  8.39MB
    unsigned short* qkvp  = (unsigned short*)(ws + 3*MB16);       // [3,6)   50.33MB
    unsigned short* kh    = (unsigned short*)(ws + 6*MB16);       // [6,7)   16.78MB
    unsigned short* qh    = (unsigned short*)(ws + MB16);         // overlays dead Wqkvh
    unsigned short* vh    = (unsigned short*)(ws);                // overlays dead xh
    unsigned short* abh   = (unsigned short*)(ws + 3*MB16);       // overlays dead qkvp

    f32_to_bf16<<<XN/1024, 256, 0, stream>>>(x,  xh,  XN);
    f32_to_bf16<<<WN/1024, 256, 0, stream>>>(Wq, Wqkvh,          WN);
    f32_to_bf16<<<WN/1024, 256, 0, stream>>>(Wk, Wqkvh +   WN,   WN);
    f32_to_bf16<<<WN/1024, 256, 0, stream>>>(Wv, Wqkvh + 2*WN,   WN);
    f32_to_bf16<<<WN/1024, 256, 0, stream>>>(Wo, Woh,            WN);

    const int M = B_ * T_;

    // fused QKV projection: [4096,2048] x [6144,2048]^T -> [4096,6144]
    gemm8<true><<<dim3(QKVN/256, M/256), 512, 0, stream>>>(xh, Wqkvh, nullptr, qkvp, M, QKVN, H_);

    rope_convert_qk<<<(B_*T_*NH_*64)/256, 256, 0, stream>>>(qkvp, cosp, sinp, qh, kh);
    transpose_v<<<dim3(T_/64, HD_/64, B_*NH_), 256, 0, stream>>>(qkvp, vh);

    attn_mfma<<<dim3(T_/64, B_*NH_), 256, 0, stream>>>(qh, kh, vh, abh);

    // output projection: [4096,2048] x [2048,2048]^T -> [4096,2048] f32
    gemm8<false><<<dim3(H_/256, M/256), 512, 0, stream>>>(abh, Woh, (float*)d_out, nullptr, M, H_, H_);
}

// Round 8
// 568.253 us; speedup vs baseline: 1.8246x; 1.8246x over previous
//
#include <hip/hip_runtime.h>
#include <hip/hip_bf16.h>

#define B_  2
#define T_  2048
#define H_  2048
#define NH_ 16
#define HD_ 128
#define QKVN 6144

typedef __attribute__((ext_vector_type(8))) short  short8;   // 8 bf16 in 4 VGPRs
typedef __attribute__((ext_vector_type(4))) float  floatx4;  // MFMA C/D

__device__ __forceinline__ unsigned short f2bf(float x) {
    union { float f; unsigned int u; } c; c.f = x;
    unsigned int r = c.u + 0x7FFF + ((c.u >> 16) & 1);   // RNE
    return (unsigned short)(r >> 16);
}
__device__ __forceinline__ float bf2f(unsigned short u) {
    union { float f; unsigned int i; } c;
    c.i = ((unsigned int)u) << 16;
    return c.f;
}

// async global->LDS, 16B per lane; LDS dest is wave-uniform base + lane*16
__device__ __forceinline__ void gload_lds16(const void* g, void* l) {
    __builtin_amdgcn_global_load_lds(
        (__attribute__((address_space(1))) void*)g,
        (__attribute__((address_space(3))) void*)l, 16, 0, 0);
}

// ---------------- fp32 -> bf16 convert (vector4) ---------------------------------
__global__ __launch_bounds__(256) void f32_to_bf16(
    const float* __restrict__ src, unsigned short* __restrict__ dst, int n)
{
    const int i = (blockIdx.x * 256 + threadIdx.x) * 4;
    if (i < n) {
        float4 v = *(const float4*)(src + i);
        ushort4 o;
        o.x = f2bf(v.x); o.y = f2bf(v.y); o.z = f2bf(v.z); o.w = f2bf(v.w);
        *(ushort4*)(dst + i) = o;
    }
}

// ---------------- gemm8 fragment helpers ------------------------------------------
template<int MB>
__device__ __forceinline__ void ld_a4(short8 (&d)[4][2], const unsigned short* src,
                                      int wm, int n16, int quad)
{
    #pragma unroll
    for (int mi = 0; mi < 4; ++mi)
        #pragma unroll
        for (int ks = 0; ks < 2; ++ks)
            d[mi][ks] = *(const short8*)(src + (wm*128 + (MB+mi)*16 + n16) * 64
                                             + (((ks*4 + quad) ^ (n16 & 7)) * 8));
}
template<int NB>
__device__ __forceinline__ void ld_b2(short8 (&d)[2][2], const unsigned short* src,
                                      int wn, int n16, int quad)
{
    #pragma unroll
    for (int ni = 0; ni < 2; ++ni)
        #pragma unroll
        for (int ks = 0; ks < 2; ++ks)
            d[ni][ks] = *(const short8*)(src + (wn*64 + (NB+ni)*16 + n16) * 64
                                             + (((ks*4 + quad) ^ (n16 & 7)) * 8));
}
// one C-quadrant x K=64: 16 MFMA
template<int MB, int NB>
__device__ __forceinline__ void mfma_q(floatx4 (&acc)[8][4],
                                       const short8 (&a)[4][2],
                                       const short8 (&b)[2][2])
{
    #pragma unroll
    for (int ks = 0; ks < 2; ++ks)
        #pragma unroll
        for (int mi = 0; mi < 4; ++mi)
            #pragma unroll
            for (int ni = 0; ni < 2; ++ni)
                acc[MB+mi][NB+ni] = __builtin_amdgcn_mfma_f32_16x16x32_bf16(
                    a[mi][ks], b[ni][ks], acc[MB+mi][NB+ni], 0, 0, 0);
}

#define BAR()   asm volatile("s_barrier" ::: "memory")
#define SBAR()  __builtin_amdgcn_sched_barrier(0)
#define LGKM(n) do { asm volatile("s_waitcnt lgkmcnt(" #n ")" ::: "memory"); SBAR(); } while (0)

// ---------------- one K-tile: balanced read-ahead quadrant phases ----------------
// Quadrant order Q00 -> Q10 -> Q01 -> Q11. Reads spread so every pre-MFMA wait
// is a COUNTED lgkmcnt, and the LO fragments are overwritten IN PLACE at P4
// (afL/bfL last read at P3 -> no extra register set; round-7's double-set
// spilled: 160 arch VGPR + 128 AGPR > 256 budget -> 834MB scratch traffic).
//   P1: afH (8 rds) + stage A(t+1) | BAR | lgkm(8)  | MFMA Q00 (afL,bfL) | BAR
//   P2: bfH (4 rds) + stage B(t+1) | BAR | lgkm(4)  | MFMA Q10 (afH,bfL) | BAR
//   P3:                                    lgkm(0)  | MFMA Q01 (afL,bfH) | BAR
//   P4: vmcnt(0) [2-phase cover] | BAR(publish) | rd afL/bfL <- buf[t+1]
//       | MFMA Q11 (afH,bfH — already waited)  | BAR
__device__ __forceinline__ void g5_tile(
    const unsigned short* Ac, const unsigned short* Bc,
    unsigned short* An, unsigned short* Bn,
    const unsigned short* A0p, const unsigned short* A1p,
    const unsigned short* B0p, const unsigned short* B1p,
    size_t hstep, size_t knext, bool pre, int tid,
    int wm, int wn, int n16, int quad,
    short8 (&afL)[4][2], short8 (&bfL)[2][2],     // LO frags: read P1/P2/P3, rewritten P4
    short8 (&afH)[4][2], short8 (&bfH)[2][2],
    floatx4 (&acc)[8][4])
{
    // ---- P1: Q(0,0) ----
    ld_a4<4>(afH, Ac, wm, n16, quad);            // 8 reads, used at P2
    if (pre) {
        gload_lds16(A0p + knext,         An + (size_t)tid * 8);
        gload_lds16(A1p + knext,         An + (size_t)(tid + 512) * 8);
        gload_lds16(A0p + knext + hstep, An + 8192 + (size_t)tid * 8);
        gload_lds16(A1p + knext + hstep, An + 8192 + (size_t)(tid + 512) * 8);
    }
    BAR();
    LGKM(8);                                     // afL+bfL (12, from prev P4) ready
    __builtin_amdgcn_s_setprio(1);
    mfma_q<0, 0>(acc, afL, bfL);
    __builtin_amdgcn_s_setprio(0);
    BAR();

    // ---- P2: Q(1,0) ----
    ld_b2<2>(bfH, Bc, wn, n16, quad);            // 4 reads, used at P3
    if (pre) {
        gload_lds16(B0p + knext,         Bn + (size_t)tid * 8);
        gload_lds16(B1p + knext,         Bn + (size_t)(tid + 512) * 8);
        gload_lds16(B0p + knext + hstep, Bn + 8192 + (size_t)tid * 8);
        gload_lds16(B1p + knext + hstep, Bn + 8192 + (size_t)(tid + 512) * 8);
    }
    BAR();
    LGKM(4);                                     // afH ready
    __builtin_amdgcn_s_setprio(1);
    mfma_q<4, 0>(acc, afH, bfL);
    __builtin_amdgcn_s_setprio(0);
    BAR();

    // ---- P3: Q(0,1) ---- (last read of afL/bfL this tile)
    LGKM(0);                                     // bfH ready
    __builtin_amdgcn_s_setprio(1);
    mfma_q<0, 2>(acc, afL, bfH);
    __builtin_amdgcn_s_setprio(0);
    BAR();

    // ---- P4: Q(1,1) ----
    asm volatile("s_waitcnt vmcnt(0)" ::: "memory");  // staging landed (~2-phase cover)
    BAR();                                            // publish buf[t+1] to all waves
    if (pre) {                                        // overwrite LO frags in place:
        ld_a4<0>(afL, An, wm, n16, quad);             // 12 reads hidden under Q11,
        ld_b2<0>(bfL, Bn, wn, n16, quad);             // drained by next P1's lgkm(8)
    }
    SBAR();
    __builtin_amdgcn_s_setprio(1);
    mfma_q<4, 2>(acc, afH, bfH);                      // operands already waited (P2/P3)
    __builtin_amdgcn_s_setprio(0);
    BAR();
}

// ---------------- 256x256 balanced-phase bf16 GEMM: Y = A[M,K] @ W[N,K]^T --------
// 8 waves (2Mx4N), BK=64, dbuf 128KB LDS, granule-XOR swizzle both-sides,
// counted lgkm/vmcnt, in-place cross-tile register read-ahead.
template<bool BF16_OUT>
__global__ __launch_bounds__(512, 1) void gemm8(
    const unsigned short* __restrict__ A,   // [M,K] bf16
    const unsigned short* __restrict__ W,   // [N,K] bf16
    float* __restrict__ Yf, unsigned short* __restrict__ Yb,
    int M, int N, int K)
{
    __shared__ __attribute__((aligned(16))) unsigned short As[2][256 * 64]; // 64 KB
    __shared__ __attribute__((aligned(16))) unsigned short Bs[2][256 * 64]; // 64 KB

    const int tid  = threadIdx.x;
    const int lane = tid & 63;
    const int n16  = lane & 15;
    const int quad = lane >> 4;
    const int w    = tid >> 6;      // 0..7
    const int wm   = w >> 2;        // 0..1  (128-row panel)
    const int wn   = w & 3;         // 0..3  (64-col panel)

    const int m0 = blockIdx.y * 256;
    const int n0 = blockIdx.x * 256;

    // staging: slot s = i*512+tid -> LDS row r = s>>3 (within half), granule s&7.
    // source granule = (s&7) ^ (r&7)  (involution; read side XORs the same way)
    const int r0  = tid >> 3;
    const int g0  = ((tid & 7) ^ (r0 & 7)) * 8;
    const unsigned short* A0p = A + (size_t)(m0 + r0) * K + g0;
    const unsigned short* A1p = A + (size_t)(m0 + 64 + r0) * K + g0;  // (r+64)&7 == r&7
    const unsigned short* B0p = W + (size_t)(n0 + r0) * K + g0;
    const unsigned short* B1p = W + (size_t)(n0 + 64 + r0) * K + g0;
    const size_t hstep = (size_t)128 * K;   // +128 rows (second half-tile)

    floatx4 acc[8][4];
    #pragma unroll
    for (int i = 0; i < 8; i++)
        #pragma unroll
        for (int j = 0; j < 4; j++) acc[i][j] = (floatx4){0.f, 0.f, 0.f, 0.f};

    const int nt = K >> 6;          // 32 for K=2048 (even; loop unrolled by 2)

    // prologue: stage tile 0 into buf 0, drain, publish, preload tile-0 LO frags
    gload_lds16(A0p,         &As[0][(size_t)tid * 8]);
    gload_lds16(A1p,         &As[0][(size_t)(tid + 512) * 8]);
    gload_lds16(A0p + hstep, &As[0][8192 + (size_t)tid * 8]);
    gload_lds16(A1p + hstep, &As[0][8192 + (size_t)(tid + 512) * 8]);
    gload_lds16(B0p,         &Bs[0][(size_t)tid * 8]);
    gload_lds16(B1p,         &Bs[0][(size_t)(tid + 512) * 8]);
    gload_lds16(B0p + hstep, &Bs[0][8192 + (size_t)tid * 8]);
    gload_lds16(B1p + hstep, &Bs[0][8192 + (size_t)(tid + 512) * 8]);
    asm volatile("s_waitcnt vmcnt(0)" ::: "memory");
    BAR();

    short8 afL[4][2], bfL[2][2], afH[4][2], bfH[2][2];
    ld_a4<0>(afL, &As[0][0], wm, n16, quad);    // 12 reads; waited at tile-0 P1 lgkm(8)
    ld_b2<0>(bfL, &Bs[0][0], wn, n16, quad);

    for (int t = 0; t < nt; t += 2) {
        g5_tile(&As[0][0], &Bs[0][0], &As[1][0], &Bs[1][0],
                A0p, A1p, B0p, B1p, hstep,
                (size_t)(t + 1) << 6, (t + 1) < nt,
                tid, wm, wn, n16, quad, afL, bfL, afH, bfH, acc);
        g5_tile(&As[1][0], &Bs[1][0], &As[0][0], &Bs[0][0],
                A0p, A1p, B0p, B1p, hstep,
                (size_t)(t + 2) << 6, (t + 2) < nt,
                tid, wm, wn, n16, quad, afL, bfL, afH, bfH, acc);
    }

    // C/D: col = lane&15, row = quad*4 + reg  (verified m89/m91)
    #pragma unroll
    for (int mi = 0; mi < 8; ++mi) {
        const size_t rb = (size_t)(m0 + wm*128 + mi*16 + quad*4);
        #pragma unroll
        for (int r = 0; r < 4; ++r) {
            const size_t row = rb + r;
            #pragma unroll
            for (int ni = 0; ni < 4; ++ni) {
                const size_t col = n0 + wn*64 + ni*16 + n16;
                if (BF16_OUT) Yb[row * N + col] = f2bf(acc[mi][ni][r]);
                else          Yf[row * N + col] = acc[mi][ni][r];
            }
        }
    }
}

// ---------------- RoPE: bf16 qkv[:, 0:4096] -> bf16 [BH][T][HD] (q scaled) -------
__global__ __launch_bounds__(256) void rope_convert_qk(
    const unsigned short* __restrict__ qkvp,   // [B*T, 6144]
    const float* __restrict__ cosp, const float* __restrict__ sinp,
    unsigned short* __restrict__ qh, unsigned short* __restrict__ kh)
{
    const int idx  = blockIdx.x * 256 + threadIdx.x;
    const int d    = idx & 63;
    const int rest = idx >> 6;
    const int h    = rest & 15;
    const int bt   = rest >> 4;
    const int t    = bt & (T_ - 1);
    const int b    = bt >> 11;                       // T_ = 2048
    const size_t ibase = (size_t)bt * QKVN + h * HD_;
    const size_t obase = (((size_t)b * NH_ + h) * T_ + t) * HD_;

    const float c0 = cosp[t*HD_ + d],      s0 = sinp[t*HD_ + d];
    const float c1 = cosp[t*HD_ + d + 64], s1 = sinp[t*HD_ + d + 64];
    const float sc = 0.08838834764831845f;           // 1/sqrt(128)

    float q0 = bf2f(qkvp[ibase + d]), q1 = bf2f(qkvp[ibase + d + 64]);
    qh[obase + d]      = f2bf((q0*c0 - q1*s0) * sc);
    qh[obase + d + 64] = f2bf((q1*c1 + q0*s1) * sc);

    float k0 = bf2f(qkvp[ibase + 2048 + d]), k1 = bf2f(qkvp[ibase + 2048 + d + 64]);
    kh[obase + d]      = f2bf(k0*c0 - k1*s0);
    kh[obase + d + 64] = f2bf(k1*c1 + k0*s1);
}

// ---------------- V transpose: qkv[:, 4096:6144] -> bf16 [BH][HD][T] -------------
__global__ __launch_bounds__(256) void transpose_v(
    const unsigned short* __restrict__ qkvp, unsigned short* __restrict__ vh)
{
    __shared__ float tile[64][65];
    const int t0 = blockIdx.x * 64;
    const int d0 = blockIdx.y * 64;
    const int bh = blockIdx.z;
    const int b  = bh >> 4, h = bh & 15;

    for (int i = threadIdx.x; i < 4096; i += 256) {
        int r = i >> 6, c = i & 63;
        tile[r][c] = bf2f(qkvp[((size_t)b*T_ + t0 + r) * QKVN + 4096 + h*HD_ + d0 + c]);
    }
    __syncthreads();
    for (int i = threadIdx.x; i < 4096; i += 256) {
        int dr = i >> 6, tc = i & 63;
        vh[((size_t)bh * HD_ + d0 + dr) * T_ + t0 + tc] = f2bf(tile[tc][dr]);  // exact round-trip
    }
}

// ---------------- MFMA flash attention (round-0 verified) ------------------------
__global__ __launch_bounds__(256, 4) void attn_mfma(
    const unsigned short* __restrict__ qh,   // [BH][T][HD] (pre-scaled)
    const unsigned short* __restrict__ kh,   // [BH][T][HD]
    const unsigned short* __restrict__ vh,   // [BH][HD][T]
    unsigned short* __restrict__ o)          // [B][T][H] bf16
{
    __shared__ __attribute__((aligned(16))) unsigned short Ks[64 * 128];   // 16 KB
    __shared__ __attribute__((aligned(16))) unsigned short Vs[128 * 64];   // 16 KB
    __shared__ __attribute__((aligned(16))) unsigned short Ps[4][16 * 64]; //  8 KB

    const int tid  = threadIdx.x;
    const int lane = tid & 63;
    const int w    = tid >> 6;
    const int n16  = lane & 15;
    const int quad = lane >> 4;

    // work-balanced bijective remap: per-CU {a,a+8,23-a,31-a} = 66 tiles, shared bh
    const int id   = blockIdx.y * gridDim.x + blockIdx.x;
    const int bh   = id & 31;
    const int a    = (id >> 5) & 7;
    const int u    = id >> 8;
    const int qblk = (u < 2) ? (a + (u << 3)) : ((23 + ((u & 1) << 3)) - a);

    const int q0w  = qblk * 64 + w * 16;

    short8 qf[4];
    {
        const size_t qbase = ((size_t)bh * T_ + q0w + n16) * HD_ + quad * 8;
        #pragma unroll
        for (int c = 0; c < 4; c++)
            qf[c] = *(const short8*)(qh + qbase + c * 32);
    }

    const int rk   = tid >> 4;
    const int gk16 = ((tid & 15) ^ (rk & 7)) * 8;
    const unsigned short* ksrc = kh + (size_t)bh * T_ * HD_ + (size_t)rk * HD_ + gk16;
    const int dv   = tid >> 3;
    const int gv16 = ((tid & 7) ^ (dv & 7)) * 8;
    const unsigned short* vsrc = vh + (size_t)bh * HD_ * T_ + (size_t)dv * T_ + gv16;

    floatx4 of[8];
    #pragma unroll
    for (int i = 0; i < 8; i++) of[i] = (floatx4){0.f, 0.f, 0.f, 0.f};
    float mrow[4], lrow[4];
    #pragma unroll
    for (int r = 0; r < 4; r++) { mrow[r] = -INFINITY; lrow[r] = 0.f; }

    const int nkv = qblk + 1;
    for (int kv = 0; kv < nkv; kv++) {
        const int kv0 = kv * 64;
        __syncthreads();
        #pragma unroll
        for (int it = 0; it < 4; it++)
            gload_lds16(ksrc + (size_t)(kv0 + it * 16) * HD_,
                        Ks + (size_t)(it * 256 + tid) * 8);
        #pragma unroll
        for (int it = 0; it < 4; it++)
            gload_lds16(vsrc + kv0 + (size_t)(it * 32) * T_,
                        Vs + (size_t)(it * 256 + tid) * 8);
        __syncthreads();   // compiler drains vmcnt(0) before s_barrier

        floatx4 s[4];
        #pragma unroll
        for (int kg = 0; kg < 4; kg++) {
            floatx4 acc = {0.f, 0.f, 0.f, 0.f};
            #pragma unroll
            for (int c = 0; c < 4; c++) {
                short8 kf = *(const short8*)(Ks + (kg*16 + n16) * 128
                                                + (((c*4 + quad) ^ (n16 & 7)) * 8));
                acc = __builtin_amdgcn_mfma_f32_16x16x32_bf16(qf[c], kf, acc, 0, 0, 0);
            }
            s[kg] = acc;
        }

        const bool needmask = (kv0 + 63 > q0w);

        float alpha[4];
        #pragma unroll
        for (int r = 0; r < 4; r++) {
            const int qrow = q0w + quad * 4 + r;
            float v0 = s[0][r], v1 = s[1][r], v2 = s[2][r], v3 = s[3][r];
            if (needmask) {
                if (kv0 +  0 + n16 > qrow) v0 = -INFINITY;
                if (kv0 + 16 + n16 > qrow) v1 = -INFINITY;
                if (kv0 + 32 + n16 > qrow) v2 = -INFINITY;
                if (kv0 + 48 + n16 > qrow) v3 = -INFINITY;
            }

            float tm = fmaxf(fmaxf(v0, v1), fmaxf(v2, v3));
            tm = fmaxf(tm, __shfl_xor(tm, 1));
            tm = fmaxf(tm, __shfl_xor(tm, 2));
            tm = fmaxf(tm, __shfl_xor(tm, 4));
            tm = fmaxf(tm, __shfl_xor(tm, 8));

            const float mnew = fmaxf(mrow[r], tm);
            const float aa   = __expf(mrow[r] - mnew);
            const float p0 = __expf(v0 - mnew), p1 = __expf(v1 - mnew);
            const float p2 = __expf(v2 - mnew), p3 = __expf(v3 - mnew);

            float ts = p0 + p1 + p2 + p3;
            ts += __shfl_xor(ts, 1);
            ts += __shfl_xor(ts, 2);
            ts += __shfl_xor(ts, 4);
            ts += __shfl_xor(ts, 8);

            lrow[r] = lrow[r] * aa + ts;
            mrow[r] = mnew;
            alpha[r] = aa;

            const int pr = quad * 4 + r;
            const int sx = pr & 7;
            unsigned short* pp = &Ps[w][pr * 64];
            const int g0p = n16 >> 3, e = n16 & 7;
            pp[((g0p    ) ^ sx) * 8 + e] = f2bf(p0);
            pp[((g0p + 2) ^ sx) * 8 + e] = f2bf(p1);
            pp[((g0p + 4) ^ sx) * 8 + e] = f2bf(p2);
            pp[((g0p + 6) ^ sx) * 8 + e] = f2bf(p3);
        }
        #pragma unroll
        for (int nt = 0; nt < 8; nt++)
            #pragma unroll
            for (int r = 0; r < 4; r++) of[nt][r] *= alpha[r];

        short8 pf0 = *(const short8*)(&Ps[w][n16 * 64 + ((quad       ^ (n16 & 7)) * 8)]);
        short8 pf1 = *(const short8*)(&Ps[w][n16 * 64 + (((quad + 4) ^ (n16 & 7)) * 8)]);
        #pragma unroll
        for (int nt = 0; nt < 8; nt++) {
            const int vr = (nt * 16 + n16) * 64;
            short8 vf0 = *(const short8*)(Vs + vr + ((quad       ^ (n16 & 7)) * 8));
            short8 vf1 = *(const short8*)(Vs + vr + (((quad + 4) ^ (n16 & 7)) * 8));
            of[nt] = __builtin_amdgcn_mfma_f32_16x16x32_bf16(pf0, vf0, of[nt], 0, 0, 0);
            of[nt] = __builtin_amdgcn_mfma_f32_16x16x32_bf16(pf1, vf1, of[nt], 0, 0, 0);
        }
    }

    const int b = bh >> 4, h = bh & 15;
    #pragma unroll
    for (int r = 0; r < 4; r++) {
        const float inv = 1.f / lrow[r];
        const size_t orow = ((size_t)b * T_ + q0w + quad*4 + r) * H_ + h * HD_;
        #pragma unroll
        for (int nt = 0; nt < 8; nt++)
            o[orow + nt*16 + n16] = f2bf(of[nt][r] * inv);
    }
}

extern "C" void kernel_launch(void* const* d_in, const int* in_sizes, int n_in,
                              void* d_out, int out_size, void* d_ws, size_t ws_size,
                              hipStream_t stream)
{
    const float* x    = (const float*)d_in[0];
    const float* cosp = (const float*)d_in[1];
    const float* sinp = (const float*)d_in[2];
    const float* Wq   = (const float*)d_in[3];
    const float* Wk   = (const float*)d_in[4];
    const float* Wv   = (const float*)d_in[5];
    const float* Wo   = (const float*)d_in[6];

    const size_t NEL  = (size_t)B_ * T_ * H_;   // 8388608
    const int    XN   = (int)NEL;
    const int    WN   = H_ * H_;                // 4194304 per weight
    char* ws = (char*)d_ws;
    const size_t MB16 = 16777216;               // 16 MiB unit

    // overlay plan (total 7*MB16 = 117.4 MB):
    unsigned short* xh    = (unsigned short*)(ws);                // [0,1)   16.78MB
    unsigned short* Wqkvh = (unsigned short*)(ws + MB16);         // [1,2.5) 25.17MB
    unsigned short* Woh   = (unsigned short*)(ws + MB16*5/2);     // [2.5,3)  8.39MB
    unsigned short* qkvp  = (unsigned short*)(ws + 3*MB16);       // [3,6)   50.33MB
    unsigned short* kh    = (unsigned short*)(ws + 6*MB16);       // [6,7)   16.78MB
    unsigned short* qh    = (unsigned short*)(ws + MB16);         // overlays dead Wqkvh
    unsigned short* vh    = (unsigned short*)(ws);                // overlays dead xh
    unsigned short* abh   = (unsigned short*)(ws + 3*MB16);       // overlays dead qkvp

    f32_to_bf16<<<XN/1024, 256, 0, stream>>>(x,  xh,  XN);
    f32_to_bf16<<<WN/1024, 256, 0, stream>>>(Wq, Wqkvh,          WN);
    f32_to_bf16<<<WN/1024, 256, 0, stream>>>(Wk, Wqkvh +   WN,   WN);
    f32_to_bf16<<<WN/1024, 256, 0, stream>>>(Wv, Wqkvh + 2*WN,   WN);
    f32_to_bf16<<<WN/1024, 256, 0, stream>>>(Wo, Woh,            WN);

    const int M = B_ * T_;

    // fused QKV projection: [4096,2048] x [6144,2048]^T -> [4096,6144]
    gemm8<true><<<dim3(QKVN/256, M/256), 512, 0, stream>>>(xh, Wqkvh, nullptr, qkvp, M, QKVN, H_);

    rope_convert_qk<<<(B_*T_*NH_*64)/256, 256, 0, stream>>>(qkvp, cosp, sinp, qh, kh);
    transpose_v<<<dim3(T_/64, HD_/64, B_*NH_), 256, 0, stream>>>(qkvp, vh);

    attn_mfma<<<dim3(T_/64, B_*NH_), 256, 0, stream>>>(qh, kh, vh, abh);

    // output projection: [4096,2048] x [2048,2048]^T -> [4096,2048] f32
    gemm8<false><<<dim3(H_/256, M/256), 512, 0, stream>>>(abh, Woh, (float*)d_out, nullptr, M, H_, H_);
}

// Round 9
// 430.478 us; speedup vs baseline: 2.4085x; 1.3201x over previous
//
#include <hip/hip_runtime.h>
#include <hip/hip_bf16.h>

#define B_  2
#define T_  2048
#define H_  2048
#define NH_ 16
#define HD_ 128
#define QKVN 6144

typedef __attribute__((ext_vector_type(8))) short  short8;   // 8 bf16 in 4 VGPRs
typedef __attribute__((ext_vector_type(4))) float  floatx4;  // MFMA C/D

__device__ __forceinline__ unsigned short f2bf(float x) {
    union { float f; unsigned int u; } c; c.f = x;
    unsigned int r = c.u + 0x7FFF + ((c.u >> 16) & 1);   // RNE
    return (unsigned short)(r >> 16);
}
__device__ __forceinline__ float bf2f(unsigned short u) {
    union { float f; unsigned int i; } c;
    c.i = ((unsigned int)u) << 16;
    return c.f;
}

// async global->LDS, 16B per lane; LDS dest is wave-uniform base + lane*16
__device__ __forceinline__ void gload_lds16(const void* g, void* l) {
    __builtin_amdgcn_global_load_lds(
        (__attribute__((address_space(1))) void*)g,
        (__attribute__((address_space(3))) void*)l, 16, 0, 0);
}

// ---------------- fp32 -> bf16 convert (vector4) ---------------------------------
__global__ __launch_bounds__(256) void f32_to_bf16(
    const float* __restrict__ src, unsigned short* __restrict__ dst, int n)
{
    const int i = (blockIdx.x * 256 + threadIdx.x) * 4;
    if (i < n) {
        float4 v = *(const float4*)(src + i);
        ushort4 o;
        o.x = f2bf(v.x); o.y = f2bf(v.y); o.z = f2bf(v.z); o.w = f2bf(v.w);
        *(ushort4*)(dst + i) = o;
    }
}

#define BAR()   asm volatile("s_barrier" ::: "memory")
#define SBAR()  __builtin_amdgcn_sched_barrier(0)
#define LGKM0() do { asm volatile("s_waitcnt lgkmcnt(0)" ::: "memory"); SBAR(); } while (0)
#define VM0()   asm volatile("s_waitcnt vmcnt(0)" ::: "memory")

// ---------------- templated fragment helpers (all indices compile-time) ----------
template<int MI, int BASE>
__device__ __forceinline__ void ldAf(short8 (&d)[MI/2][2], const unsigned short* src,
                                     int wm, int n16, int quad)
{
    #pragma unroll
    for (int mi = 0; mi < MI/2; ++mi)
        #pragma unroll
        for (int ks = 0; ks < 2; ++ks)
            d[mi][ks] = *(const short8*)(src + (wm*(MI*16) + (BASE+mi)*16 + n16) * 64
                                             + (((ks*4 + quad) ^ (n16 & 7)) * 8));
}
template<int NI, int BASE>
__device__ __forceinline__ void ldBf(short8 (&d)[NI/2][2], const unsigned short* src,
                                     int wn, int n16, int quad)
{
    #pragma unroll
    for (int ni = 0; ni < NI/2; ++ni)
        #pragma unroll
        for (int ks = 0; ks < 2; ++ks)
            d[ni][ks] = *(const short8*)(src + (wn*(NI*16) + (BASE+ni)*16 + n16) * 64
                                             + (((ks*4 + quad) ^ (n16 & 7)) * 8));
}
// one C-quadrant x K=64
template<int MI, int NI, int MB, int NB>
__device__ __forceinline__ void mq(floatx4 (&acc)[MI][NI],
                                   const short8 (&a)[MI/2][2],
                                   const short8 (&b)[NI/2][2])
{
    #pragma unroll
    for (int ks = 0; ks < 2; ++ks)
        #pragma unroll
        for (int mi = 0; mi < MI/2; ++mi)
            #pragma unroll
            for (int ni = 0; ni < NI/2; ++ni)
                acc[MB+mi][NB+ni] = __builtin_amdgcn_mfma_f32_16x16x32_bf16(
                    a[mi][ks], b[ni][ks], acc[MB+mi][NB+ni], 0, 0, 0);
}

// ---------------- one K-tile: round-5-verified quadrant phases -------------------
//   P1: rd aL+bL | stage A(t+1) | BAR | lgkm0 | MFMA Q00 (aL,bL) | BAR
//   P2: rd bH    | stage B(t+1) | BAR | lgkm0 | MFMA Q01 (aL,bH) | BAR
//   P3: rd aH    |                BAR | lgkm0 | MFMA Q10 (aH,bL) | BAR
//   P4: vmcnt(0) [staging has ~2-phase cover] | BAR(publish) | MFMA Q11 (aH,bH) | BAR
// All frags in-tile only (no cross-tile live ranges: rounds 7/8 proved those
// spill past the 256-reg unified-file wall -> 150-700MB scratch traffic).
template<int MI, int NI>
__device__ __forceinline__ void gt_tile(
    const unsigned short* Ac, const unsigned short* Bc,
    unsigned short* An, unsigned short* Bn,
    const unsigned short* Ap, const unsigned short* Bp,
    size_t knext, bool pre, int tid, int K,
    int wm, int wn, int n16, int quad,
    floatx4 (&acc)[MI][NI])
{
    constexpr int MH = MI/2, NH = NI/2;
    constexpr int AG = (MI*32)/64;   // A gloads per tile (64 rows each)
    constexpr int BG = (NI*64)/64;   // B gloads per tile

    short8 aL[MH][2], aH[MH][2], bL[NH][2], bH[NH][2];

    // ---- P1: Q(0,0) ----
    ldAf<MI, 0>(aL, Ac, wm, n16, quad);
    ldBf<NI, 0>(bL, Bc, wn, n16, quad);
    if (pre) {
        #pragma unroll
        for (int h = 0; h < AG; ++h)
            gload_lds16(Ap + knext + (size_t)h * 64 * K, An + h * 4096 + (size_t)tid * 8);
    }
    BAR();
    LGKM0();
    __builtin_amdgcn_s_setprio(1);
    mq<MI, NI, 0, 0>(acc, aL, bL);
    __builtin_amdgcn_s_setprio(0);
    BAR();

    // ---- P2: Q(0,1) ----
    ldBf<NI, NH>(bH, Bc, wn, n16, quad);
    if (pre) {
        #pragma unroll
        for (int h = 0; h < BG; ++h)
            gload_lds16(Bp + knext + (size_t)h * 64 * K, Bn + h * 4096 + (size_t)tid * 8);
    }
    BAR();
    LGKM0();
    __builtin_amdgcn_s_setprio(1);
    mq<MI, NI, 0, NH>(acc, aL, bH);
    __builtin_amdgcn_s_setprio(0);
    BAR();

    // ---- P3: Q(1,0) ----
    ldAf<MI, MH>(aH, Ac, wm, n16, quad);
    BAR();
    LGKM0();
    __builtin_amdgcn_s_setprio(1);
    mq<MI, NI, MH, 0>(acc, aH, bL);
    __builtin_amdgcn_s_setprio(0);
    BAR();

    // ---- P4: Q(1,1) ----
    VM0();                     // staging landed (issued P1/P2, ~2-phase cover)
    BAR();                     // publish buf[t+1] to all waves
    SBAR();
    __builtin_amdgcn_s_setprio(1);
    mq<MI, NI, MH, NH>(acc, aH, bH);
    __builtin_amdgcn_s_setprio(0);
    BAR();
}

// ---------------- tiled bf16 GEMM: Y[M,N] = A[M,K] @ W[N,K]^T --------------------
// 8 waves (2M x 4N), per-wave MI x NI 16-frags. BM=MI*32, BN=NI*64.
// QKV: <4,6> -> 128x384, grid 16x32 = 512 blocks = 2.0 full rounds (packing 1.0).
// Wo:  <4,4> -> 128x256, grid  8x32 = 256 blocks = 1.0 round   (packing 1.0).
// BK=64, dbuf LDS, granule-XOR swizzle both-sides (round-5 verified skeleton).
template<int MI, int NI, bool BF16_OUT>
__global__ __launch_bounds__(512, 1) void gemm_t(
    const unsigned short* __restrict__ A,   // [M,K] bf16
    const unsigned short* __restrict__ W,   // [N,K] bf16
    float* __restrict__ Yf, unsigned short* __restrict__ Yb,
    int M, int N, int K)
{
    constexpr int BM = MI*32, BN = NI*64;
    constexpr int AG = BM/64, BG = BN/64;
    __shared__ __attribute__((aligned(16))) unsigned short As[2][BM * 64];
    __shared__ __attribute__((aligned(16))) unsigned short Bs[2][BN * 64];

    const int tid  = threadIdx.x;
    const int lane = tid & 63;
    const int n16  = lane & 15;
    const int quad = lane >> 4;
    const int w    = tid >> 6;      // 0..7
    const int wm   = w >> 2;        // 0..1  (M panel)
    const int wn   = w & 3;         // 0..3  (N panel)

    const int m0 = blockIdx.y * BM;
    const int n0 = blockIdx.x * BN;

    // staging: slot s = tid -> LDS row r = tid>>3 (64 rows/gload), granule tid&7.
    // source granule = (tid&7) ^ (r&7); (r+64)&7 == r&7 so one base serves all h.
    const int r0  = tid >> 3;
    const int g0  = ((tid & 7) ^ (r0 & 7)) * 8;
    const unsigned short* Ap = A + (size_t)(m0 + r0) * K + g0;
    const unsigned short* Bp = W + (size_t)(n0 + r0) * K + g0;

    floatx4 acc[MI][NI];
    #pragma unroll
    for (int i = 0; i < MI; i++)
        #pragma unroll
        for (int j = 0; j < NI; j++) acc[i][j] = (floatx4){0.f, 0.f, 0.f, 0.f};

    const int nt = K >> 6;          // 32 for K=2048 (even; loop unrolled by 2)

    // prologue: stage tile 0 into buf 0, drain, publish
    #pragma unroll
    for (int h = 0; h < AG; ++h)
        gload_lds16(Ap + (size_t)h * 64 * K, &As[0][h * 4096 + (size_t)tid * 8]);
    #pragma unroll
    for (int h = 0; h < BG; ++h)
        gload_lds16(Bp + (size_t)h * 64 * K, &Bs[0][h * 4096 + (size_t)tid * 8]);
    VM0();
    BAR();

    for (int t = 0; t < nt; t += 2) {
        gt_tile<MI, NI>(&As[0][0], &Bs[0][0], &As[1][0], &Bs[1][0],
                        Ap, Bp, (size_t)(t + 1) << 6, (t + 1) < nt,
                        tid, K, wm, wn, n16, quad, acc);
        gt_tile<MI, NI>(&As[1][0], &Bs[1][0], &As[0][0], &Bs[0][0],
                        Ap, Bp, (size_t)(t + 2) << 6, (t + 2) < nt,
                        tid, K, wm, wn, n16, quad, acc);
    }

    // C/D: col = lane&15, row = quad*4 + reg  (verified m89/m91)
    #pragma unroll
    for (int mi = 0; mi < MI; ++mi) {
        const size_t rb = (size_t)(m0 + wm*(MI*16) + mi*16 + quad*4);
        #pragma unroll
        for (int r = 0; r < 4; ++r) {
            const size_t row = rb + r;
            #pragma unroll
            for (int ni = 0; ni < NI; ++ni) {
                const size_t col = n0 + wn*(NI*16) + ni*16 + n16;
                if (BF16_OUT) Yb[row * N + col] = f2bf(acc[mi][ni][r]);
                else          Yf[row * N + col] = acc[mi][ni][r];
            }
        }
    }
}

// ---------------- RoPE: bf16 qkv[:, 0:4096] -> bf16 [BH][T][HD] (q scaled) -------
__global__ __launch_bounds__(256) void rope_convert_qk(
    const unsigned short* __restrict__ qkvp,   // [B*T, 6144]
    const float* __restrict__ cosp, const float* __restrict__ sinp,
    unsigned short* __restrict__ qh, unsigned short* __restrict__ kh)
{
    const int idx  = blockIdx.x * 256 + threadIdx.x;
    const int d    = idx & 63;
    const int rest = idx >> 6;
    const int h    = rest & 15;
    const int bt   = rest >> 4;
    const int t    = bt & (T_ - 1);
    const int b    = bt >> 11;                       // T_ = 2048
    const size_t ibase = (size_t)bt * QKVN + h * HD_;
    const size_t obase = (((size_t)b * NH_ + h) * T_ + t) * HD_;

    const float c0 = cosp[t*HD_ + d],      s0 = sinp[t*HD_ + d];
    const float c1 = cosp[t*HD_ + d + 64], s1 = sinp[t*HD_ + d + 64];
    const float sc = 0.08838834764831845f;           // 1/sqrt(128)

    float q0 = bf2f(qkvp[ibase + d]), q1 = bf2f(qkvp[ibase + d + 64]);
    qh[obase + d]      = f2bf((q0*c0 - q1*s0) * sc);
    qh[obase + d + 64] = f2bf((q1*c1 + q0*s1) * sc);

    float k0 = bf2f(qkvp[ibase + 2048 + d]), k1 = bf2f(qkvp[ibase + 2048 + d + 64]);
    kh[obase + d]      = f2bf(k0*c0 - k1*s0);
    kh[obase + d + 64] = f2bf(k1*c1 + k0*s1);
}

// ---------------- V transpose: qkv[:, 4096:6144] -> bf16 [BH][HD][T] -------------
__global__ __launch_bounds__(256) void transpose_v(
    const unsigned short* __restrict__ qkvp, unsigned short* __restrict__ vh)
{
    __shared__ float tile[64][65];
    const int t0 = blockIdx.x * 64;
    const int d0 = blockIdx.y * 64;
    const int bh = blockIdx.z;
    const int b  = bh >> 4, h = bh & 15;

    for (int i = threadIdx.x; i < 4096; i += 256) {
        int r = i >> 6, c = i & 63;
        tile[r][c] = bf2f(qkvp[((size_t)b*T_ + t0 + r) * QKVN + 4096 + h*HD_ + d0 + c]);
    }
    __syncthreads();
    for (int i = threadIdx.x; i < 4096; i += 256) {
        int dr = i >> 6, tc = i & 63;
        vh[((size_t)bh * HD_ + d0 + dr) * T_ + t0 + tc] = f2bf(tile[tc][dr]);  // exact round-trip
    }
}

// ---------------- MFMA flash attention (round-0 verified) ------------------------
__global__ __launch_bounds__(256, 4) void attn_mfma(
    const unsigned short* __restrict__ qh,   // [BH][T][HD] (pre-scaled)
    const unsigned short* __restrict__ kh,   // [BH][T][HD]
    const unsigned short* __restrict__ vh,   // [BH][HD][T]
    unsigned short* __restrict__ o)          // [B][T][H] bf16
{
    __shared__ __attribute__((aligned(16))) unsigned short Ks[64 * 128];   // 16 KB
    __shared__ __attribute__((aligned(16))) unsigned short Vs[128 * 64];   // 16 KB
    __shared__ __attribute__((aligned(16))) unsigned short Ps[4][16 * 64]; //  8 KB

    const int tid  = threadIdx.x;
    const int lane = tid & 63;
    const int w    = tid >> 6;
    const int n16  = lane & 15;
    const int quad = lane >> 4;

    // work-balanced bijective remap: per-CU {a,a+8,23-a,31-a} = 66 tiles, shared bh
    const int id   = blockIdx.y * gridDim.x + blockIdx.x;
    const int bh   = id & 31;
    const int a    = (id >> 5) & 7;
    const int u    = id >> 8;
    const int qblk = (u < 2) ? (a + (u << 3)) : ((23 + ((u & 1) << 3)) - a);

    const int q0w  = qblk * 64 + w * 16;

    short8 qf[4];
    {
        const size_t qbase = ((size_t)bh * T_ + q0w + n16) * HD_ + quad * 8;
        #pragma unroll
        for (int c = 0; c < 4; c++)
            qf[c] = *(const short8*)(qh + qbase + c * 32);
    }

    const int rk   = tid >> 4;
    const int gk16 = ((tid & 15) ^ (rk & 7)) * 8;
    const unsigned short* ksrc = kh + (size_t)bh * T_ * HD_ + (size_t)rk * HD_ + gk16;
    const int dv   = tid >> 3;
    const int gv16 = ((tid & 7) ^ (dv & 7)) * 8;
    const unsigned short* vsrc = vh + (size_t)bh * HD_ * T_ + (size_t)dv * T_ + gv16;

    floatx4 of[8];
    #pragma unroll
    for (int i = 0; i < 8; i++) of[i] = (floatx4){0.f, 0.f, 0.f, 0.f};
    float mrow[4], lrow[4];
    #pragma unroll
    for (int r = 0; r < 4; r++) { mrow[r] = -INFINITY; lrow[r] = 0.f; }

    const int nkv = qblk + 1;
    for (int kv = 0; kv < nkv; kv++) {
        const int kv0 = kv * 64;
        __syncthreads();
        #pragma unroll
        for (int it = 0; it < 4; it++)
            gload_lds16(ksrc + (size_t)(kv0 + it * 16) * HD_,
                        Ks + (size_t)(it * 256 + tid) * 8);
        #pragma unroll
        for (int it = 0; it < 4; it++)
            gload_lds16(vsrc + kv0 + (size_t)(it * 32) * T_,
                        Vs + (size_t)(it * 256 + tid) * 8);
        __syncthreads();   // compiler drains vmcnt(0) before s_barrier

        floatx4 s[4];
        #pragma unroll
        for (int kg = 0; kg < 4; kg++) {
            floatx4 acc = {0.f, 0.f, 0.f, 0.f};
            #pragma unroll
            for (int c = 0; c < 4; c++) {
                short8 kf = *(const short8*)(Ks + (kg*16 + n16) * 128
                                                + (((c*4 + quad) ^ (n16 & 7)) * 8));
                acc = __builtin_amdgcn_mfma_f32_16x16x32_bf16(qf[c], kf, acc, 0, 0, 0);
            }
            s[kg] = acc;
        }

        const bool needmask = (kv0 + 63 > q0w);

        float alpha[4];
        #pragma unroll
        for (int r = 0; r < 4; r++) {
            const int qrow = q0w + quad * 4 + r;
            float v0 = s[0][r], v1 = s[1][r], v2 = s[2][r], v3 = s[3][r];
            if (needmask) {
                if (kv0 +  0 + n16 > qrow) v0 = -INFINITY;
                if (kv0 + 16 + n16 > qrow) v1 = -INFINITY;
                if (kv0 + 32 + n16 > qrow) v2 = -INFINITY;
                if (kv0 + 48 + n16 > qrow) v3 = -INFINITY;
            }

            float tm = fmaxf(fmaxf(v0, v1), fmaxf(v2, v3));
            tm = fmaxf(tm, __shfl_xor(tm, 1));
            tm = fmaxf(tm, __shfl_xor(tm, 2));
            tm = fmaxf(tm, __shfl_xor(tm, 4));
            tm = fmaxf(tm, __shfl_xor(tm, 8));

            const float mnew = fmaxf(mrow[r], tm);
            const float aa   = __expf(mrow[r] - mnew);
            const float p0 = __expf(v0 - mnew), p1 = __expf(v1 - mnew);
            const float p2 = __expf(v2 - mnew), p3 = __expf(v3 - mnew);

            float ts = p0 + p1 + p2 + p3;
            ts += __shfl_xor(ts, 1);
            ts += __shfl_xor(ts, 2);
            ts += __shfl_xor(ts, 4);
            ts += __shfl_xor(ts, 8);

            lrow[r] = lrow[r] * aa + ts;
            mrow[r] = mnew;
            alpha[r] = aa;

            const int pr = quad * 4 + r;
            const int sx = pr & 7;
            unsigned short* pp = &Ps[w][pr * 64];
            const int g0p = n16 >> 3, e = n16 & 7;
            pp[((g0p    ) ^ sx) * 8 + e] = f2bf(p0);
            pp[((g0p + 2) ^ sx) * 8 + e] = f2bf(p1);
            pp[((g0p + 4) ^ sx) * 8 + e] = f2bf(p2);
            pp[((g0p + 6) ^ sx) * 8 + e] = f2bf(p3);
        }
        #pragma unroll
        for (int nt = 0; nt < 8; nt++)
            #pragma unroll
            for (int r = 0; r < 4; r++) of[nt][r] *= alpha[r];

        short8 pf0 = *(const short8*)(&Ps[w][n16 * 64 + ((quad       ^ (n16 & 7)) * 8)]);
        short8 pf1 = *(const short8*)(&Ps[w][n16 * 64 + (((quad + 4) ^ (n16 & 7)) * 8)]);
        #pragma unroll
        for (int nt = 0; nt < 8; nt++) {
            const int vr = (nt * 16 + n16) * 64;
            short8 vf0 = *(const short8*)(Vs + vr + ((quad       ^ (n16 & 7)) * 8));
            short8 vf1 = *(const short8*)(Vs + vr + (((quad + 4) ^ (n16 & 7)) * 8));
            of[nt] = __builtin_amdgcn_mfma_f32_16x16x32_bf16(pf0, vf0, of[nt], 0, 0, 0);
            of[nt] = __builtin_amdgcn_mfma_f32_16x16x32_bf16(pf1, vf1, of[nt], 0, 0, 0);
        }
    }

    const int b = bh >> 4, h = bh & 15;
    #pragma unroll
    for (int r = 0; r < 4; r++) {
        const float inv = 1.f / lrow[r];
        const size_t orow = ((size_t)b * T_ + q0w + quad*4 + r) * H_ + h * HD_;
        #pragma unroll
        for (int nt = 0; nt < 8; nt++)
            o[orow + nt*16 + n16] = f2bf(of[nt][r] * inv);
    }
}

extern "C" void kernel_launch(void* const* d_in, const int* in_sizes, int n_in,
                              void* d_out, int out_size, void* d_ws, size_t ws_size,
                              hipStream_t stream)
{
    const float* x    = (const float*)d_in[0];
    const float* cosp = (const float*)d_in[1];
    const float* sinp = (const float*)d_in[2];
    const float* Wq   = (const float*)d_in[3];
    const float* Wk   = (const float*)d_in[4];
    const float* Wv   = (const float*)d_in[5];
    const float* Wo   = (const float*)d_in[6];

    const size_t NEL  = (size_t)B_ * T_ * H_;   // 8388608
    const int    XN   = (int)NEL;
    const int    WN   = H_ * H_;                // 4194304 per weight
    char* ws = (char*)d_ws;
    const size_t MB16 = 16777216;               // 16 MiB unit

    // overlay plan (total 7*MB16 = 117.4 MB):
    unsigned short* xh    = (unsigned short*)(ws);                // [0,1)   16.78MB
    unsigned short* Wqkvh = (unsigned short*)(ws + MB16);         // [1,2.5) 25.17MB
    unsigned short* Woh   = (unsigned short*)(ws + MB16*5/2);     // [2.5,3)  8.39MB
    unsigned short* qkvp  = (unsigned short*)(ws + 3*MB16);       // [3,6)   50.33MB
    unsigned short* kh    = (unsigned short*)(ws + 6*MB16);       // [6,7)   16.78MB
    unsigned short* qh    = (unsigned short*)(ws + MB16);         // overlays dead Wqkvh
    unsigned short* vh    = (unsigned short*)(ws);                // overlays dead xh
    unsigned short* abh   = (unsigned short*)(ws + 3*MB16);       // overlays dead qkvp

    f32_to_bf16<<<XN/1024, 256, 0, stream>>>(x,  xh,  XN);
    f32_to_bf16<<<WN/1024, 256, 0, stream>>>(Wq, Wqkvh,          WN);
    f32_to_bf16<<<WN/1024, 256, 0, stream>>>(Wk, Wqkvh +   WN,   WN);
    f32_to_bf16<<<WN/1024, 256, 0, stream>>>(Wv, Wqkvh + 2*WN,   WN);
    f32_to_bf16<<<WN/1024, 256, 0, stream>>>(Wo, Woh,            WN);

    const int M = B_ * T_;

    // fused QKV projection: [4096,2048] x [6144,2048]^T -> [4096,6144]
    // 128x384 tile -> 16x32 = 512 blocks = 2.0 full rounds
    gemm_t<4, 6, true><<<dim3(QKVN/384, M/128), 512, 0, stream>>>(
        xh, Wqkvh, nullptr, qkvp, M, QKVN, H_);

    rope_convert_qk<<<(B_*T_*NH_*64)/256, 256, 0, stream>>>(qkvp, cosp, sinp, qh, kh);
    transpose_v<<<dim3(T_/64, HD_/64, B_*NH_), 256, 0, stream>>>(qkvp, vh);

    attn_mfma<<<dim3(T_/64, B_*NH_), 256, 0, stream>>>(qh, kh, vh, abh);

    // output projection: [4096,2048] x [2048,2048]^T -> [4096,2048] f32
    // 128x256 tile -> 8x32 = 256 blocks = 1.0 round
    gemm_t<4, 4, false><<<dim3(H_/256, M/128), 512, 0, stream>>>(
        abh, Woh, (float*)d_out, nullptr, M, H_, H_);
}